// Round 13
// baseline (275.094 us; speedup 1.0000x reference)
//
#include <hip/hip_runtime.h>
#include <math.h>

#define NT     512
#define NWAVES 8
#define GB     4
#define NTOK   20
#define NTT_P  5          // token tiles for 80-row phases

typedef _Float16 f16x8 __attribute__((ext_vector_type(8)));
typedef _Float16 f16x4 __attribute__((ext_vector_type(4)));
typedef _Float16 half2v __attribute__((ext_vector_type(2)));
typedef float    f32x4 __attribute__((ext_vector_type(4)));

__device__ __forceinline__ float fdot2(half2v a, half2v b, float c)
{
#if __has_builtin(__builtin_amdgcn_fdot2)
    return __builtin_amdgcn_fdot2(a, b, c, false);
#else
    return c + (float)a.x * (float)b.x + (float)a.y * (float)b.y;
#endif
}

// ---- ws fp16 section: transposed, zero-padded weights W_T[n][kpad] --------
#define WS_W1A  0        // [160][32]   (N=150,K=13)
#define WS_W1B  5120     // [112][160]  (N=100,K=150)
#define WS_WA0  23040    // [112][128]  (N=100,K=100)  wa0 rows 0..99
#define WS_WA1  37376    // [112][128]
#define WS_W2A  51712    // [112][128]
#define WS_W2B  66048    // [64][128]   (N=50,K=100)
#define WS_W3A  74240    // [160][64]   (N=150,K=56)
#define WS_W3B  84480    // [112][160]  (N=100,K=150)
#define WS_W3C  102400   // [112][128]  (N=100,K=100)
#define WS_WA0H 116736   // [112][128]  wa0 rows 100..199 (g part)
#define WS_TOTAL 131072
// ---- ws f32 bias section (zero-padded), float index from ws base ----------
#define WB_BASE 65536    // = WS_TOTAL/2 (f32 units)
#define WB_B1A  0
#define WB_B1B  160
#define WB_BA0  272
#define WB_BA1  384
#define WB_B2A  496
#define WB_B2B  608
#define WB_B3A  672
#define WB_B3B  832
#define WB_B3C  944
#define WB_WA2  1056
#define WB_N    1168
#define PREP_TOTAL (WS_TOTAL + WB_N)

// ---- LDS arena (halves), 52.9 KB -> 3 blocks/CU ---------------------------
// A [0,12160)    : t1[80][152] -> s1[80][136] -> f1[80][136]
// B [12160,23040): h1[80][136] -> f[80][72]
// C [23040,26240): x[80][40] -> gq strips [4][104] -> part(f32) -> tail strips
#define LH_A    0
#define LH_B    12160
#define LH_C    23040
#define LH_T1   LH_A          // stride 152
#define LH_S1   LH_A          // stride 136
#define LH_F1   LH_A          // stride 136
#define LH_H1   LH_B          // stride 136
#define LH_FF   LH_B          // [80][72]
// tail strips in C (part dead): mvS[4][64], haS[4][160], hbS[4][112], hcS[4][112]
#define LH_MVS  (LH_C + 0)
#define LH_HAS  (LH_C + 256)
#define LH_HBS  (LH_C + 896)
#define LH_HCS  (LH_C + 1344)
#define LF_PART 11520         // f32: part [80][8]  (= LH_C/2)
#define LF_GB   12672         // f32: gbias [4][112]
#define LF_ATT  13120         // f32: att [80]
#define LF_SS   13200         // f32: ss [24]
#define LDS_DW  13224
#define LDS_BYTES (LDS_DW * 4)   // 52896 B

// ---------------------------------------------------------------------------
// prep: W_T[n][k] = (fp16) W[k][N..] zero-padded; plus zero-padded f32 biases
// ---------------------------------------------------------------------------
__device__ __forceinline__ void prep_one(const float* __restrict__ src, _Float16* dst,
                                         int local, int N, int K, int Ks)
{
    int n = local / Ks, k = local - n * Ks;
    dst[local] = (_Float16)((n < N && k < K) ? src[k * N + n] : 0.f);
}
__device__ __forceinline__ void prep_b(const float* __restrict__ src, float* dst,
                                       int idx, int N)
{
    dst[idx] = (idx < N) ? src[idx] : 0.f;
}

__global__ __launch_bounds__(256)
void prep_kernel(const float* __restrict__ w1a, const float* __restrict__ w1b,
                 const float* __restrict__ wa0, const float* __restrict__ wa1,
                 const float* __restrict__ w2a, const float* __restrict__ w2b,
                 const float* __restrict__ w3a, const float* __restrict__ w3b,
                 const float* __restrict__ w3c, const float* __restrict__ wa2,
                 const float* __restrict__ b1a, const float* __restrict__ b1b,
                 const float* __restrict__ ba0, const float* __restrict__ ba1,
                 const float* __restrict__ b2a, const float* __restrict__ b2b,
                 const float* __restrict__ b3a, const float* __restrict__ b3b,
                 const float* __restrict__ b3c,
                 _Float16* __restrict__ ws)
{
    int g = blockIdx.x * 256 + threadIdx.x;
    if (g >= PREP_TOTAL) return;
    if (g >= WS_TOTAL) {
        float* wb = (float*)ws + WB_BASE;
        int l = g - WS_TOTAL;
        if (l < WB_B1B)      prep_b(b1a, wb + WB_B1A, l - WB_B1A, 150);
        else if (l < WB_BA0) prep_b(b1b, wb + WB_B1B, l - WB_B1B, 100);
        else if (l < WB_BA1) prep_b(ba0, wb + WB_BA0, l - WB_BA0, 100);
        else if (l < WB_B2A) prep_b(ba1, wb + WB_BA1, l - WB_BA1, 100);
        else if (l < WB_B2B) prep_b(b2a, wb + WB_B2A, l - WB_B2A, 100);
        else if (l < WB_B3A) prep_b(b2b, wb + WB_B2B, l - WB_B2B, 50);
        else if (l < WB_B3B) prep_b(b3a, wb + WB_B3A, l - WB_B3A, 150);
        else if (l < WB_B3C) prep_b(b3b, wb + WB_B3B, l - WB_B3B, 100);
        else if (l < WB_WA2) prep_b(b3c, wb + WB_B3C, l - WB_B3C, 100);
        else                 prep_b(wa2, wb + WB_WA2, l - WB_WA2, 100);
        return;
    }
    if (g < WS_W1B)       prep_one(w1a, ws + WS_W1A, g - WS_W1A, 150, 13, 32);
    else if (g < WS_WA0)  prep_one(w1b, ws + WS_W1B, g - WS_W1B, 100, 150, 160);
    else if (g < WS_WA1)  prep_one(wa0, ws + WS_WA0, g - WS_WA0, 100, 100, 128);
    else if (g < WS_W2A)  prep_one(wa1, ws + WS_WA1, g - WS_WA1, 100, 100, 128);
    else if (g < WS_W2B)  prep_one(w2a, ws + WS_W2A, g - WS_W2A, 100, 100, 128);
    else if (g < WS_W3A)  prep_one(w2b, ws + WS_W2B, g - WS_W2B,  50, 100, 128);
    else if (g < WS_W3B)  prep_one(w3a, ws + WS_W3A, g - WS_W3A, 150,  56, 64);
    else if (g < WS_W3C)  prep_one(w3b, ws + WS_W3B, g - WS_W3B, 100, 150, 160);
    else if (g < WS_WA0H) prep_one(w3c, ws + WS_W3C, g - WS_W3C, 100, 100, 128);
    else                  prep_one(wa0 + 100 * 100, ws + WS_WA0H, g - WS_WA0H, 100, 100, 128);
}

// ---------------------------------------------------------------------------
// Swapped-operand GEMM (R9 schedule), NW = participating waves.
// OMODE 0: fp16 Y[token][feat] b64 store, clamped fb<CLW.
// OMODE 2: scores-partial: y=relu(s2); p=y.wa2p; kq-reduce shfl_xor(16/32);
//          kq==0 stores part[token*8+mt].
// BMODE 0: padded f32 biasp. 1: gbias[token/20][feat..].
// ---------------------------------------------------------------------------
template<int KT, int MTL, int NTT, bool RELU, int BMODE, int OMODE, int CLW, int NW>
__device__ __forceinline__ void gemm_sw(const _Float16* X, const int Xs,
                                        const _Float16* __restrict__ WT, const int Bs,
                                        const float* __restrict__ biasp,
                                        const float* gbias,
                                        _Float16* Y, const int Ys,
                                        float* part, const float* __restrict__ wa2p,
                                        const int wv, const int lane)
{
    const int cl = lane & 15, kq = lane >> 4;
    constexpr int IPW = (MTL + NW - 1) / NW;
    f16x8 wf[IPW][KT];
    f32x4 bv[IPW];
#pragma unroll
    for (int ii = 0; ii < IPW; ++ii) {
        const int mt = wv + ii * NW;
        if (mt < MTL) {
            const _Float16* Wp = WT + (mt * 16 + cl) * Bs + kq * 8;
#pragma unroll
            for (int kt = 0; kt < KT; ++kt) wf[ii][kt] = *(const f16x8*)(Wp + kt * 32);
            if (BMODE == 0)
                bv[ii] = *(const f32x4*)(biasp + mt * 16 + kq * 4);
        }
    }
#pragma unroll
    for (int ii = 0; ii < IPW; ++ii) {
        const int mt = wv + ii * NW;
        if (mt >= MTL) break;
        const int fb = mt * 16 + kq * 4;
#pragma unroll
        for (int nt = 0; nt < NTT; ++nt) {
            const _Float16* Xp = X + (nt * 16 + cl) * Xs + kq * 8;
            f16x8 xf[KT];
#pragma unroll
            for (int kt = 0; kt < KT; ++kt) xf[kt] = *(const f16x8*)(Xp + kt * 32);
            f32x4 acc = {0.f, 0.f, 0.f, 0.f};
#pragma unroll
            for (int kt = 0; kt < KT; ++kt)
                acc = __builtin_amdgcn_mfma_f32_16x16x32_f16(wf[ii][kt], xf[kt], acc, 0, 0, 0);
            const int token = nt * 16 + cl;
            if (OMODE == 2) {
                f32x4 y = acc + bv[ii];
                y[0] = fmaxf(y[0], 0.f); y[1] = fmaxf(y[1], 0.f);
                y[2] = fmaxf(y[2], 0.f); y[3] = fmaxf(y[3], 0.f);
                f32x4 w4 = *(const f32x4*)(wa2p + fb);
                float p = y[0] * w4[0] + y[1] * w4[1] + y[2] * w4[2] + y[3] * w4[3];
                p += __shfl_xor(p, 16);
                p += __shfl_xor(p, 32);
                if (kq == 0) part[token * 8 + mt] = p;
            } else {
                f32x4 bb;
                if (BMODE == 1)
                    bb = *(const f32x4*)(gbias + (token / NTOK) * 112 + fb);
                else
                    bb = bv[ii];
                f32x4 y = acc + bb;
                if (RELU) {
                    y[0] = fmaxf(y[0], 0.f); y[1] = fmaxf(y[1], 0.f);
                    y[2] = fmaxf(y[2], 0.f); y[3] = fmaxf(y[3], 0.f);
                }
                if (fb < CLW) {
                    f16x4 o = { (_Float16)y[0], (_Float16)y[1],
                                (_Float16)y[2], (_Float16)y[3] };
                    *(f16x4*)(Y + token * Ys + fb) = o;
                }
            }
        }
    }
}

// ---------------------------------------------------------------------------
// Wave-local dense layer: each lane computes outputs n = lane, lane+64, ...
// x-row is a wave-shared LDS strip (broadcast reads); W rows from ws (L1-hot).
// Two accumulators break the fdot2 dependence chain.
// ---------------------------------------------------------------------------
template<int NOUT, int KC, bool RELU>
__device__ __forceinline__ void wave_dot(const _Float16* __restrict__ xrow,
                                         const _Float16* __restrict__ WT, const int Bs,
                                         const float* __restrict__ biasp,
                                         _Float16* __restrict__ ydst, const int lane)
{
#pragma unroll
    for (int nn = 0; nn < (NOUT + 63) / 64; ++nn) {
        const int n = lane + nn * 64;
        if (n < NOUT) {
            float a0 = biasp[n], a1 = 0.f;
            const _Float16* wr = WT + n * Bs;
#pragma unroll
            for (int c = 0; c < KC; ++c) {
                f16x8 xa = *(const f16x8*)(xrow + c * 8);
                f16x8 wl = *(const f16x8*)(wr + c * 8);
                a0 = fdot2((half2v){xa[0], xa[1]}, (half2v){wl[0], wl[1]}, a0);
                a1 = fdot2((half2v){xa[2], xa[3]}, (half2v){wl[2], wl[3]}, a1);
                a0 = fdot2((half2v){xa[4], xa[5]}, (half2v){wl[4], wl[5]}, a0);
                a1 = fdot2((half2v){xa[6], xa[7]}, (half2v){wl[6], wl[7]}, a1);
            }
            float acc = a0 + a1;
            if (RELU) acc = fmaxf(acc, 0.f);
            ydst[n] = (_Float16)acc;
        }
    }
}

__global__ __launch_bounds__(NT, 6)
void vnet_kernel(const float* __restrict__ x,
                 const float* __restrict__ ba2,
                 const float* __restrict__ w3d, const float* __restrict__ b3d,
                 const _Float16* __restrict__ wsh,
                 float* __restrict__ outp)
{
    extern __shared__ float lds_f[];
    _Float16* lds_h = (_Float16*)lds_f;

    const int tid  = threadIdx.x;
    const int lane = tid & 63, wv = tid >> 6;
    const int b0   = blockIdx.x * GB;
    const float* wb = (const float*)wsh + WB_BASE;

    _Float16* xa  = lds_h + LH_C;
    float* gbias = lds_f + LF_GB;
    float* att   = lds_f + LF_ATT;
    float* ss    = lds_f + LF_SS;
    float* part  = lds_f + LF_PART;

    // ---- P0: zero arena (finite base for all pad/overflow reads) ---------
    for (int i = tid; i < LDS_DW; i += NT) lds_f[i] = 0.f;
    __syncthreads();

    // ---- P1: x -> C row-major [token][40]; self_state --------------------
    const float* xg = x + (size_t)b0 * (NTOK * 13);
    for (int t = tid; t < GB * NTOK * 13; t += NT) {
        int row = t / 13, d = t - row * 13;
        xa[row * 40 + d] = (_Float16)xg[t];
    }
    if (tid < GB * 6) {
        int b = tid / 6, d = tid - b * 6;
        ss[tid] = xg[b * (NTOK * 13) + d];   // x[b,0,d]
    }
    __syncthreads();

    // ---- P2: t1 = relu(x @ w1a + b1a) -> A [80][152], stores fb<152 ------
    gemm_sw<1, 10, NTT_P, true, 0, 0, 152, 8>(xa, 40, wsh + WS_W1A, 32,
        wb + WB_B1A, nullptr, lds_h + LH_T1, 152, nullptr, nullptr, wv, lane);
    __syncthreads();

    // ---- P3: h1 = relu(t1 @ w1b + b1b) -> B [80][136] --------------------
    // (row-end spill reads hit zero-padded W1B k-rows: finite x 0 = 0)
    gemm_sw<5, 7, NTT_P, true, 0, 0, 10000, 8>(lds_h + LH_T1, 152, wsh + WS_W1B,
        160, wb + WB_B1B, nullptr, lds_h + LH_H1, 136, nullptr, nullptr, wv, lane);
    __syncthreads();

    // ---- M0: wave b (b<4): gq[b] column-sums, then gbias[b] wave-dots ----
    const _Float16* h1 = lds_h + LH_H1;
    if (wv < GB) {
        const int b = wv;
        _Float16* gqS = lds_h + LH_C + b * 104;   // x dead; stale pads finite
        for (int c = lane; c < 100; c += 64) {
            float s = 0.f;
#pragma unroll
            for (int n = 0; n < NTOK; ++n) s += (float)h1[(b * NTOK + n) * 136 + c];
            gqS[c] = (_Float16)(s * (1.f / NTOK));
        }
        // gbias[b][n] = ba0p[n] + gq[b] . wa0_hi_T[n]  (13 chunks = 104 halves;
        // gq pads 100..103 stale-finite x WA0H zero k-rows)
        float* gbB = gbias + b * 112;
#pragma unroll
        for (int nn = 0; nn < 2; ++nn) {
            const int n = lane + nn * 64;
            if (n < 112) {
                float a0 = wb[WB_BA0 + n], a1 = 0.f;
                const _Float16* wr = wsh + WS_WA0H + n * 128;
#pragma unroll
                for (int c = 0; c < 13; ++c) {
                    f16x8 xq = *(const f16x8*)(gqS + c * 8);
                    f16x8 wl = *(const f16x8*)(wr + c * 8);
                    a0 = fdot2((half2v){xq[0], xq[1]}, (half2v){wl[0], wl[1]}, a0);
                    a1 = fdot2((half2v){xq[2], xq[3]}, (half2v){wl[2], wl[3]}, a1);
                    a0 = fdot2((half2v){xq[4], xq[5]}, (half2v){wl[4], wl[5]}, a0);
                    a1 = fdot2((half2v){xq[6], xq[7]}, (half2v){wl[6], wl[7]}, a1);
                }
                gbB[n] = a0 + a1;
            }
        }
    }
    __syncthreads();

    // ---- M1: s1 = relu(h1 @ wa0_lo + gbias) -> A (t1 dead) ---------------
    gemm_sw<4, 7, NTT_P, true, 1, 0, 10000, 8>(h1, 136, wsh + WS_WA0, 128,
        nullptr, gbias, lds_h + LH_S1, 136, nullptr, nullptr, wv, lane);
    __syncthreads();

    // ---- M2: s2-scores partials from s1 (no s2 store) -> part ------------
    gemm_sw<4, 7, NTT_P, true, 0, 2, 10000, 8>(lds_h + LH_S1, 136, wsh + WS_WA1,
        128, wb + WB_BA1, nullptr, nullptr, 0, part, wb + WB_WA2, wv, lane);
    __syncthreads();

    // ---- M3: f1 = relu(h1 @ w2a + b2a) -> A (s1 dead) --------------------
    gemm_sw<4, 7, NTT_P, true, 0, 0, 10000, 8>(h1, 136, wsh + WS_W2A, 128,
        wb + WB_B2A, nullptr, lds_h + LH_F1, 136, nullptr, nullptr, wv, lane);
    __syncthreads();

    // ---- M4: f = f1 @ w2b + b2b -> B head [80][72] (waves 0-3, h1 dead);
    //          att-sum + softmax wave-synchronous on waves 4-7 -------------
    if (wv < 4) {
        gemm_sw<4, 4, NTT_P, false, 0, 0, 10000, 4>(lds_h + LH_F1, 136,
            wsh + WS_W2B, 128, wb + WB_B2B, nullptr, lds_h + LH_FF, 72,
            nullptr, nullptr, wv, lane);
    } else {
        const int b = wv - 4;
        float sc = -1e30f;
        if (lane < NTOK) {
            sc = ba2[0];
            const float* pr = part + (b * NTOK + lane) * 8;
#pragma unroll
            for (int m = 0; m < 7; ++m) sc += pr[m];
        }
        float mx = sc;
#pragma unroll
        for (int off = 16; off; off >>= 1) mx = fmaxf(mx, __shfl_xor(mx, off, 32));
        float e = (lane < NTOK) ? expf(sc - mx) : 0.f;
        float s = e;
#pragma unroll
        for (int off = 16; off; off >>= 1) s += __shfl_xor(s, off, 32);
        if (lane < NTOK) att[b * NTOK + lane] = e / s;
    }
    __syncthreads();

    // ---- TAIL: wave b (b<4) runs its whole 56->150->100->100->1 MLP
    //            wave-locally (no barriers). Strips live in C (part dead). --
    if (wv < GB) {
        const int b = wv;
        _Float16* mvS = lds_h + LH_MVS + b * 64;
        _Float16* haS = lds_h + LH_HAS + b * 160;
        _Float16* hbS = lds_h + LH_HBS + b * 112;
        _Float16* hcS = lds_h + LH_HCS + b * 112;
        const _Float16* fh = lds_h + LH_FF;

        // mv = [ss | wf]
        if (lane < 56) {
            float v;
            if (lane < 6) {
                v = ss[b * 6 + lane];
            } else {
                const int cc = lane - 6;
                const float* ab = att + b * NTOK;
                float acc = 0.f;
#pragma unroll
                for (int n = 0; n < NTOK; ++n)
                    acc = fmaf((float)fh[(b * NTOK + n) * 72 + cc], ab[n], acc);
                v = acc;
            }
            mvS[lane] = (_Float16)v;
        }
        // T1: ha(160 incl. auto-zero pads) = relu(mv @ w3a + b3a), K=56
        wave_dot<160, 7, true>(mvS, wsh + WS_W3A, 64, wb + WB_B3A, haS, lane);
        // T2: hb(112) = relu(ha @ w3b + b3b), K=160 (pads zero both sides)
        wave_dot<112, 20, true>(haS, wsh + WS_W3B, 160, wb + WB_B3B, hbS, lane);
        // T3: hc(112) = relu(hb @ w3c + b3c), K=112
        wave_dot<112, 14, true>(hbS, wsh + WS_W3C, 128, wb + WB_B3C, hcS, lane);
        // T4: out = hc . w3d + b3d
        float acc = 0.f;
        for (int k = lane; k < 100; k += 64)
            acc = fmaf((float)hcS[k], w3d[k], acc);
#pragma unroll
        for (int off = 32; off; off >>= 1) acc += __shfl_xor(acc, off);
        if (lane == 0) outp[b0 + b] = acc + b3d[0];
    }
}

extern "C" void kernel_launch(void* const* d_in, const int* in_sizes, int n_in,
                              void* d_out, int out_size, void* d_ws, size_t ws_size,
                              hipStream_t stream)
{
    const float* x   = (const float*)d_in[0];
    const float* w1a = (const float*)d_in[1];
    const float* b1a = (const float*)d_in[2];
    const float* w1b = (const float*)d_in[3];
    const float* b1b = (const float*)d_in[4];
    const float* wa0 = (const float*)d_in[5];
    const float* ba0 = (const float*)d_in[6];
    const float* wa1 = (const float*)d_in[7];
    const float* ba1 = (const float*)d_in[8];
    const float* wa2 = (const float*)d_in[9];
    const float* ba2 = (const float*)d_in[10];
    const float* w2a = (const float*)d_in[11];
    const float* b2a = (const float*)d_in[12];
    const float* w2b = (const float*)d_in[13];
    const float* b2b = (const float*)d_in[14];
    const float* w3a = (const float*)d_in[15];
    const float* b3a = (const float*)d_in[16];
    const float* w3b = (const float*)d_in[17];
    const float* b3b = (const float*)d_in[18];
    const float* w3c = (const float*)d_in[19];
    const float* b3c = (const float*)d_in[20];
    const float* w3d = (const float*)d_in[21];
    const float* b3d = (const float*)d_in[22];
    float* outp = (float*)d_out;
    _Float16* wsh = (_Float16*)d_ws;

    hipFuncSetAttribute((const void*)vnet_kernel,
                        hipFuncAttributeMaxDynamicSharedMemorySize, LDS_BYTES);

    hipLaunchKernelGGL(prep_kernel, dim3((PREP_TOTAL + 255) / 256), dim3(256),
                       0, stream,
                       w1a, w1b, wa0, wa1, w2a, w2b, w3a, w3b, w3c, wa2,
                       b1a, b1b, ba0, ba1, b2a, b2b, b3a, b3b, b3c, wsh);

    const int B = 16384;
    hipLaunchKernelGGL(vnet_kernel, dim3(B / GB), dim3(NT), LDS_BYTES, stream,
                       x, ba2, w3d, b3d, wsh, outp);
}

// Round 14
// 119.553 us; speedup vs baseline: 2.3010x; 2.3010x over previous
//
#include <hip/hip_runtime.h>
#include <math.h>

#define NT     512
#define NWAVES 8
#define GB     4
#define NTOK   20
#define NTT_P  5          // token tiles for 80-row phases

typedef _Float16 f16x8 __attribute__((ext_vector_type(8)));
typedef _Float16 f16x4 __attribute__((ext_vector_type(4)));
typedef _Float16 f16x2 __attribute__((ext_vector_type(2)));
typedef float    f32x4 __attribute__((ext_vector_type(4)));

// ---- ws fp16 section: transposed, zero-padded weights W_T[n][kpad] --------
#define WS_W1A  0        // [160][32]   (N=150,K=13)
#define WS_W1B  5120     // [112][160]  (N=100,K=150)
#define WS_WA0  23040    // [112][128]  (N=100,K=100)  wa0 rows 0..99
#define WS_WA1  37376    // [112][128]
#define WS_W2A  51712    // [112][128]
#define WS_W2B  66048    // [64][128]   (N=50,K=100)
#define WS_W3A  74240    // [160][64]   (N=150,K=56)
#define WS_W3B  84480    // [112][160]  (N=100,K=150)
#define WS_W3C  102400   // [112][128]  (N=100,K=100)
#define WS_WA0H 116736   // [112][128]  wa0 rows 100..199 (g part)
#define WS_TOTAL 131072
// ---- ws f32 bias section (zero-padded) ------------------------------------
#define WB_BASE 65536    // f32 units from ws base
#define WB_B1A  0
#define WB_B1B  160
#define WB_BA0  272
#define WB_BA1  384
#define WB_B2A  496
#define WB_B2B  608
#define WB_B3A  672
#define WB_B3B  832
#define WB_B3C  944
#define WB_WA2  1056
#define WB_N    1168
#define PREP_TOTAL (WS_TOTAL + WB_N)
// ---- mv staging: fp16 [B][64] at half-offset 135168 (past bias section) ---
#define WS_MV   135168

// ---- main-kernel LDS arena (halves), 52.9 KB -> 3 blocks/CU ---------------
// A [0,12160)    : t1[80][152] -> s1[80][136] -> f1[80][136]
// B [12160,23040): h1[80][136] -> f[80][72]
// C [23040,26240): x[80][40] -> gq strips -> part(f32)
#define LH_A    0
#define LH_B    12160
#define LH_C    23040
#define LH_T1   LH_A          // stride 152
#define LH_S1   LH_A          // stride 136
#define LH_F1   LH_A          // stride 136
#define LH_H1   LH_B          // stride 136
#define LH_FF   LH_B          // [80][72]
#define LH_GQ   LH_C          // [16][136] strip (rows 0..3 real)
#define LF_PART 11520         // f32: part [80][8]
#define LF_GB   12672         // f32: gbias [4][112]
#define LF_ATT  13120         // f32: att [80]
#define LF_SS   13200         // f32: ss [24]
#define LDS_DW  13224
#define LDS_BYTES (LDS_DW * 4)   // 52896 B

// ---- tail-kernel LDS arena (halves): 64 batches/block ---------------------
#define TB      64
#define TL_MV   0        // [64][64]
#define TL_HA   4096     // [64][168]
#define TL_HB   14848    // [64][136]
#define TL_HC   23552    // [64][136] -> end 32256
#define LDS_T_DW   16128
#define LDS_T_BYTES (LDS_T_DW * 4)   // 64512 B

// ---------------------------------------------------------------------------
// prep: W_T[n][k] = (fp16) W[k][N..] zero-padded; plus zero-padded f32 biases
// ---------------------------------------------------------------------------
__device__ __forceinline__ void prep_one(const float* __restrict__ src, _Float16* dst,
                                         int local, int N, int K, int Ks)
{
    int n = local / Ks, k = local - n * Ks;
    dst[local] = (_Float16)((n < N && k < K) ? src[k * N + n] : 0.f);
}
__device__ __forceinline__ void prep_b(const float* __restrict__ src, float* dst,
                                       int idx, int N)
{
    dst[idx] = (idx < N) ? src[idx] : 0.f;
}

__global__ __launch_bounds__(256)
void prep_kernel(const float* __restrict__ w1a, const float* __restrict__ w1b,
                 const float* __restrict__ wa0, const float* __restrict__ wa1,
                 const float* __restrict__ w2a, const float* __restrict__ w2b,
                 const float* __restrict__ w3a, const float* __restrict__ w3b,
                 const float* __restrict__ w3c, const float* __restrict__ wa2,
                 const float* __restrict__ b1a, const float* __restrict__ b1b,
                 const float* __restrict__ ba0, const float* __restrict__ ba1,
                 const float* __restrict__ b2a, const float* __restrict__ b2b,
                 const float* __restrict__ b3a, const float* __restrict__ b3b,
                 const float* __restrict__ b3c,
                 _Float16* __restrict__ ws)
{
    int g = blockIdx.x * 256 + threadIdx.x;
    if (g >= PREP_TOTAL) return;
    if (g >= WS_TOTAL) {
        float* wb = (float*)ws + WB_BASE;
        int l = g - WS_TOTAL;
        if (l < WB_B1B)      prep_b(b1a, wb + WB_B1A, l - WB_B1A, 150);
        else if (l < WB_BA0) prep_b(b1b, wb + WB_B1B, l - WB_B1B, 100);
        else if (l < WB_BA1) prep_b(ba0, wb + WB_BA0, l - WB_BA0, 100);
        else if (l < WB_B2A) prep_b(ba1, wb + WB_BA1, l - WB_BA1, 100);
        else if (l < WB_B2B) prep_b(b2a, wb + WB_B2A, l - WB_B2A, 100);
        else if (l < WB_B3A) prep_b(b2b, wb + WB_B2B, l - WB_B2B, 50);
        else if (l < WB_B3B) prep_b(b3a, wb + WB_B3A, l - WB_B3A, 150);
        else if (l < WB_B3C) prep_b(b3b, wb + WB_B3B, l - WB_B3B, 100);
        else if (l < WB_WA2) prep_b(b3c, wb + WB_B3C, l - WB_B3C, 100);
        else                 prep_b(wa2, wb + WB_WA2, l - WB_WA2, 100);
        return;
    }
    if (g < WS_W1B)       prep_one(w1a, ws + WS_W1A, g - WS_W1A, 150, 13, 32);
    else if (g < WS_WA0)  prep_one(w1b, ws + WS_W1B, g - WS_W1B, 100, 150, 160);
    else if (g < WS_WA1)  prep_one(wa0, ws + WS_WA0, g - WS_WA0, 100, 100, 128);
    else if (g < WS_W2A)  prep_one(wa1, ws + WS_WA1, g - WS_WA1, 100, 100, 128);
    else if (g < WS_W2B)  prep_one(w2a, ws + WS_W2A, g - WS_W2A, 100, 100, 128);
    else if (g < WS_W3A)  prep_one(w2b, ws + WS_W2B, g - WS_W2B,  50, 100, 128);
    else if (g < WS_W3B)  prep_one(w3a, ws + WS_W3A, g - WS_W3A, 150,  56, 64);
    else if (g < WS_W3C)  prep_one(w3b, ws + WS_W3B, g - WS_W3B, 100, 150, 160);
    else if (g < WS_WA0H) prep_one(w3c, ws + WS_W3C, g - WS_W3C, 100, 100, 128);
    else                  prep_one(wa0 + 100 * 100, ws + WS_WA0H, g - WS_WA0H, 100, 100, 128);
}

// ---------------------------------------------------------------------------
// Swapped-operand GEMM (R9/R12-proven schedule), NW = participating waves.
// D[feature][token]; lane (cl,kq) holds feats mt*16+kq*4+r for token nt*16+cl.
// OMODE 0: fp16 Y[token][feat] b64 store, clamped fb<CLW.
// OMODE 1: f32x4 -> gbias[token][feat] (token<GB).
// OMODE 2: scores-partial: y=relu(s2); p=y.wa2p; kq-reduce shfl_xor(16/32);
//          kq==0 stores part[token*8+mt].
// BMODE 0: padded f32 biasp. 1: gbias[token/20][feat..].
// ---------------------------------------------------------------------------
template<int KT, int MTL, int NTT, bool RELU, int BMODE, int OMODE, int CLW, int NW>
__device__ __forceinline__ void gemm_sw(const _Float16* X, const int Xs,
                                        const _Float16* __restrict__ WT, const int Bs,
                                        const float* __restrict__ biasp,
                                        const float* gbias,
                                        _Float16* Y, const int Ys,
                                        float* part, const float* __restrict__ wa2p,
                                        const int wv, const int lane)
{
    const int cl = lane & 15, kq = lane >> 4;
    constexpr int IPW = (MTL + NW - 1) / NW;
    f16x8 wf[IPW][KT];
    f32x4 bv[IPW];
#pragma unroll
    for (int ii = 0; ii < IPW; ++ii) {
        const int mt = wv + ii * NW;
        if (mt < MTL) {
            const _Float16* Wp = WT + (mt * 16 + cl) * Bs + kq * 8;
#pragma unroll
            for (int kt = 0; kt < KT; ++kt) wf[ii][kt] = *(const f16x8*)(Wp + kt * 32);
            if (BMODE == 0)
                bv[ii] = *(const f32x4*)(biasp + mt * 16 + kq * 4);
        }
    }
#pragma unroll
    for (int ii = 0; ii < IPW; ++ii) {
        const int mt = wv + ii * NW;
        if (mt >= MTL) break;
        const int fb = mt * 16 + kq * 4;
#pragma unroll
        for (int nt = 0; nt < NTT; ++nt) {
            const _Float16* Xp = X + (nt * 16 + cl) * Xs + kq * 8;
            f16x8 xf[KT];
#pragma unroll
            for (int kt = 0; kt < KT; ++kt) xf[kt] = *(const f16x8*)(Xp + kt * 32);
            f32x4 acc = {0.f, 0.f, 0.f, 0.f};
#pragma unroll
            for (int kt = 0; kt < KT; ++kt)
                acc = __builtin_amdgcn_mfma_f32_16x16x32_f16(wf[ii][kt], xf[kt], acc, 0, 0, 0);
            const int token = nt * 16 + cl;
            if (OMODE == 1) {
                if (cl < GB) {
                    f32x4 o = acc + bv[ii];
                    *(f32x4*)((float*)Y + cl * 112 + fb) = o;
                }
            } else if (OMODE == 2) {
                f32x4 y = acc + bv[ii];
                y[0] = fmaxf(y[0], 0.f); y[1] = fmaxf(y[1], 0.f);
                y[2] = fmaxf(y[2], 0.f); y[3] = fmaxf(y[3], 0.f);
                f32x4 w4 = *(const f32x4*)(wa2p + fb);
                float p = y[0] * w4[0] + y[1] * w4[1] + y[2] * w4[2] + y[3] * w4[3];
                p += __shfl_xor(p, 16);
                p += __shfl_xor(p, 32);
                if (kq == 0) part[token * 8 + mt] = p;
            } else {
                f32x4 bb;
                if (BMODE == 1)
                    bb = *(const f32x4*)(gbias + (token / NTOK) * 112 + fb);
                else
                    bb = bv[ii];
                f32x4 y = acc + bb;
                if (RELU) {
                    y[0] = fmaxf(y[0], 0.f); y[1] = fmaxf(y[1], 0.f);
                    y[2] = fmaxf(y[2], 0.f); y[3] = fmaxf(y[3], 0.f);
                }
                if (fb < CLW) {
                    f16x4 o = { (_Float16)y[0], (_Float16)y[1],
                                (_Float16)y[2], (_Float16)y[3] };
                    *(f16x4*)(Y + token * Ys + fb) = o;
                }
            }
        }
    }
}

// ===========================================================================
// MAIN kernel: phases P1..M4 + mv->global. 10 barriers.
// ===========================================================================
__global__ __launch_bounds__(NT, 6)
void vnet_kernel(const float* __restrict__ x,
                 const float* __restrict__ ba2,
                 const _Float16* __restrict__ wsh,
                 _Float16* __restrict__ mvg)
{
    extern __shared__ float lds_f[];
    _Float16* lds_h = (_Float16*)lds_f;

    const int tid  = threadIdx.x;
    const int lane = tid & 63, wv = tid >> 6;
    const int b0   = blockIdx.x * GB;
    const float* wb = (const float*)wsh + WB_BASE;

    _Float16* xa  = lds_h + LH_C;
    _Float16* gqh = lds_h + LH_GQ;
    _Float16* h1w = lds_h + LH_H1;
    float* gbias = lds_f + LF_GB;
    float* att   = lds_f + LF_ATT;
    float* ss    = lds_f + LF_SS;
    float* part  = lds_f + LF_PART;

    // ---- P1: x -> C row-major [token][40]; targeted pad zeroing ----------
    // (replaces R12's full-arena zero: xa cols 13..39, h1 cols 112..135,
    //  h1[0][0..7] for the benign t1 row-79 spill — all other pad reads are
    //  written-this-launch-finite x zero-padded weights)
    const float* xg = x + (size_t)b0 * (NTOK * 13);
    for (int t = tid; t < GB * NTOK * 13; t += NT) {
        int row = t / 13, d = t - row * 13;
        xa[row * 40 + d] = (_Float16)xg[t];
    }
    for (int t = tid; t < 80 * 27; t += NT) {
        int row = t / 27, c = 13 + (t - row * 27);
        xa[row * 40 + c] = (_Float16)0.f;
    }
    for (int t = tid; t < 80 * 24; t += NT) {
        int row = t / 24, c = 112 + (t - row * 24);
        h1w[row * 136 + c] = (_Float16)0.f;
    }
    if (tid < 8) h1w[tid] = (_Float16)0.f;
    if (tid < GB * 6) {
        int b = tid / 6, d = tid - b * 6;
        ss[tid] = xg[b * (NTOK * 13) + d];   // x[b,0,d]
    }
    __syncthreads();

    // ---- P2: t1 = relu(x @ w1a + b1a) -> A [80][152], stores fb<152 ------
    gemm_sw<1, 10, NTT_P, true, 0, 0, 152, 8>(xa, 40, wsh + WS_W1A, 32,
        wb + WB_B1A, nullptr, lds_h + LH_T1, 152, nullptr, nullptr, wv, lane);
    __syncthreads();

    // ---- P3: h1 = relu(t1 @ w1b + b1b) -> B [80][136] --------------------
    gemm_sw<5, 7, NTT_P, true, 0, 0, 10000, 8>(lds_h + LH_T1, 152, wsh + WS_W1B,
        160, wb + WB_B1B, nullptr, h1w, 136, nullptr, nullptr, wv, lane);
    __syncthreads();

    // ---- P4: gq[b][c] = mean_n h1 (u32-paired) -> fp16 strip @ C ---------
    const _Float16* h1 = h1w;
    const uint* h1u = (const uint*)h1;
    for (int t = tid; t < GB * 50; t += NT) {
        int b = t / 50, cp = t - b * 50;
        float s0 = 0.f, s1 = 0.f;
#pragma unroll
        for (int n = 0; n < NTOK; ++n) {
            uint v = h1u[(b * NTOK + n) * 68 + cp];
            f16x2 p = *(const f16x2*)&v;
            s0 += (float)p.x; s1 += (float)p.y;
        }
        f16x2 g = { (_Float16)(s0 * 0.05f), (_Float16)(s1 * 0.05f) };
        *(f16x2*)(gqh + b * 136 + 2 * cp) = g;
    }
    __syncthreads();

    // ---- Mg: gbias = ba0 + gq @ wa0_hi (f32 out) -------------------------
    gemm_sw<4, 7, 1, false, 0, 1, 10000, 8>(gqh, 136, wsh + WS_WA0H, 128,
        wb + WB_BA0, nullptr, (_Float16*)gbias, 0, nullptr, nullptr, wv, lane);
    __syncthreads();

    // ---- M1: s1 = relu(h1 @ wa0_lo + gbias) -> A (t1 dead) ---------------
    gemm_sw<4, 7, NTT_P, true, 1, 0, 10000, 8>(h1, 136, wsh + WS_WA0, 128,
        nullptr, gbias, lds_h + LH_S1, 136, nullptr, nullptr, wv, lane);
    __syncthreads();

    // ---- M2: s2-scores partials from s1 (no s2 store) -> part ------------
    gemm_sw<4, 7, NTT_P, true, 0, 2, 10000, 8>(lds_h + LH_S1, 136, wsh + WS_WA1,
        128, wb + WB_BA1, nullptr, nullptr, 0, part, wb + WB_WA2, wv, lane);
    __syncthreads();

    // ---- M3: f1 = relu(h1 @ w2a + b2a) -> A (s1 dead) --------------------
    gemm_sw<4, 7, NTT_P, true, 0, 0, 10000, 8>(h1, 136, wsh + WS_W2A, 128,
        wb + WB_B2A, nullptr, lds_h + LH_F1, 136, nullptr, nullptr, wv, lane);
    __syncthreads();

    // ---- M4: f = f1 @ w2b + b2b -> B head [80][72] (waves 0-3, h1 dead);
    //          att-sum + softmax wave-synchronous on waves 4-7 -------------
    if (wv < 4) {
        gemm_sw<4, 4, NTT_P, false, 0, 0, 10000, 4>(lds_h + LH_F1, 136,
            wsh + WS_W2B, 128, wb + WB_B2B, nullptr, lds_h + LH_FF, 72,
            nullptr, nullptr, wv, lane);
    } else {
        const int b = wv - 4;
        float sc = -1e30f;
        if (lane < NTOK) {
            sc = ba2[0];
            const float* pr = part + (b * NTOK + lane) * 8;
#pragma unroll
            for (int m = 0; m < 7; ++m) sc += pr[m];
        }
        float mx = sc;
#pragma unroll
        for (int off = 16; off; off >>= 1) mx = fmaxf(mx, __shfl_xor(mx, off, 32));
        float e = (lane < NTOK) ? expf(sc - mx) : 0.f;
        float s = e;
#pragma unroll
        for (int off = 16; off; off >>= 1) s += __shfl_xor(s, off, 32);
        if (lane < NTOK) att[b * NTOK + lane] = e / s;
    }
    __syncthreads();

    // ---- P10: mv[b][c] = [ss | wf | 0-pad] -> GLOBAL fp16 [B][64] --------
    const _Float16* fh = lds_h + LH_FF;
    for (int t = tid; t < GB * 64; t += NT) {
        int b = t >> 6, c = t & 63;
        float v = 0.f;
        if (c < 6) {
            v = ss[b * 6 + c];
        } else if (c < 56) {
            const int cc = c - 6;
            const float* ab = att + b * NTOK;
            float acc = 0.f;
#pragma unroll
            for (int n = 0; n < NTOK; ++n)
                acc = fmaf((float)fh[(b * NTOK + n) * 72 + cc], ab[n], acc);
            v = acc;
        }
        mvg[(size_t)(b0 + b) * 64 + c] = (_Float16)v;
    }
}

// ===========================================================================
// TAIL kernel: 64 batches/block, 256 blocks; mv -> 150 -> 100 -> 100 -> 1
// ===========================================================================
__global__ __launch_bounds__(NT)
void tail_kernel(const _Float16* __restrict__ mvg,
                 const float* __restrict__ w3d, const float* __restrict__ b3d,
                 const _Float16* __restrict__ wsh,
                 float* __restrict__ outp)
{
    extern __shared__ float lds_f[];
    _Float16* lds_h = (_Float16*)lds_f;

    const int tid  = threadIdx.x;
    const int lane = tid & 63, wv = tid >> 6;
    const int g0   = blockIdx.x * TB;
    const float* wb = (const float*)wsh + WB_BASE;

    // ---- L: load mv [64][64] + zero HB region (cols 112..127 NaN-safety) -
    _Float16* mvT = lds_h + TL_MV;
    {
        const uint* src = (const uint*)(mvg + (size_t)g0 * 64);
        uint* dst = (uint*)mvT;
        for (int t = tid; t < TB * 32; t += NT) dst[t] = src[t];
    }
    for (int t = tid; t < (TL_HC - TL_HB) / 2; t += NT)
        ((uint*)(lds_h + TL_HB))[t] = 0u;
    __syncthreads();

    // ---- T1: ha = relu(mv @ w3a + b3a)  [64][168], K=64 ------------------
    gemm_sw<2, 10, 4, true, 0, 0, 10000, 8>(mvT, 64, wsh + WS_W3A, 64,
        wb + WB_B3A, nullptr, lds_h + TL_HA, 168, nullptr, nullptr, wv, lane);
    __syncthreads();

    // ---- T2: hb = relu(ha @ w3b + b3b)  [64][136], K=160 -----------------
    gemm_sw<5, 7, 4, true, 0, 0, 10000, 8>(lds_h + TL_HA, 168, wsh + WS_W3B,
        160, wb + WB_B3B, nullptr, lds_h + TL_HB, 136, nullptr, nullptr, wv, lane);
    __syncthreads();

    // ---- T3: hc = relu(hb @ w3c + b3c)  [64][136], K=128 -----------------
    gemm_sw<4, 7, 4, true, 0, 0, 10000, 8>(lds_h + TL_HB, 136, wsh + WS_W3C,
        128, wb + WB_B3C, nullptr, lds_h + TL_HC, 136, nullptr, nullptr, wv, lane);
    __syncthreads();

    // ---- T4: out = hc . w3d + b3d  (8 lanes per batch) -------------------
    {
        const int b = tid >> 3, kl = tid & 7;
        const _Float16* hc = lds_h + TL_HC + b * 136;
        float acc = 0.f;
#pragma unroll 13
        for (int k = kl; k < 100; k += 8)
            acc = fmaf((float)hc[k], w3d[k], acc);
        acc += __shfl_xor(acc, 1);
        acc += __shfl_xor(acc, 2);
        acc += __shfl_xor(acc, 4);
        if (kl == 0) outp[g0 + b] = acc + b3d[0];
    }
}

extern "C" void kernel_launch(void* const* d_in, const int* in_sizes, int n_in,
                              void* d_out, int out_size, void* d_ws, size_t ws_size,
                              hipStream_t stream)
{
    const float* x   = (const float*)d_in[0];
    const float* w1a = (const float*)d_in[1];
    const float* b1a = (const float*)d_in[2];
    const float* w1b = (const float*)d_in[3];
    const float* b1b = (const float*)d_in[4];
    const float* wa0 = (const float*)d_in[5];
    const float* ba0 = (const float*)d_in[6];
    const float* wa1 = (const float*)d_in[7];
    const float* ba1 = (const float*)d_in[8];
    const float* wa2 = (const float*)d_in[9];
    const float* ba2 = (const float*)d_in[10];
    const float* w2a = (const float*)d_in[11];
    const float* b2a = (const float*)d_in[12];
    const float* w2b = (const float*)d_in[13];
    const float* b2b = (const float*)d_in[14];
    const float* w3a = (const float*)d_in[15];
    const float* b3a = (const float*)d_in[16];
    const float* w3b = (const float*)d_in[17];
    const float* b3b = (const float*)d_in[18];
    const float* w3c = (const float*)d_in[19];
    const float* b3c = (const float*)d_in[20];
    const float* w3d = (const float*)d_in[21];
    const float* b3d = (const float*)d_in[22];
    float* outp = (float*)d_out;
    _Float16* wsh = (_Float16*)d_ws;
    _Float16* mvg = wsh + WS_MV;

    hipFuncSetAttribute((const void*)vnet_kernel,
                        hipFuncAttributeMaxDynamicSharedMemorySize, LDS_BYTES);
    hipFuncSetAttribute((const void*)tail_kernel,
                        hipFuncAttributeMaxDynamicSharedMemorySize, LDS_T_BYTES);

    hipLaunchKernelGGL(prep_kernel, dim3((PREP_TOTAL + 255) / 256), dim3(256),
                       0, stream,
                       w1a, w1b, wa0, wa1, w2a, w2b, w3a, w3b, w3c, wa2,
                       b1a, b1b, ba0, ba1, b2a, b2b, b3a, b3b, b3c, wsh);

    const int B = 16384;
    hipLaunchKernelGGL(vnet_kernel, dim3(B / GB), dim3(NT), LDS_BYTES, stream,
                       x, ba2, wsh, mvg);
    hipLaunchKernelGGL(tail_kernel, dim3(B / TB), dim3(NT), LDS_T_BYTES, stream,
                       mvg, w3d, b3d, wsh, outp);
}